// Round 2
// baseline (476.074 us; speedup 1.0000x reference)
//
#include <hip/hip_runtime.h>

#define B_SZ 256
#define C_SZ 1152
#define M_SZ 8
#define O_SZ 16
#define I_SZ 8
#define SPLIT 9
#define CPB (C_SZ / SPLIT)   // 128 capsules per block
#define CAPS_EPS 1e-8f

// One routing pass, C-split across SPLIT blocks per batch element.
// grid = SPLIT * B (split = blockIdx.x / B, b = blockIdx.x % B so that
// concurrently-dispatched blocks share the same 512KB W slice in L2).
// block = 256 threads = 32 capsule-groups x 8 m-lanes.
//
// Partial sums (pre-reduction s) go to part_out[SPLIT][B][128]; the NEXT
// pass's prologue reduces them (deterministic, no atomics).
//
// R=0: c uniform -> part_out
// R=1: s0 = reduce(part_in); v0 = squash(s0) (split 0 stores v0);
//      logits = u_hat . v0 -> part_out
// R=2: s1 = reduce(part_in); v1 = squash(s1); vsum = v0 + v1;
//      logits = u_hat . vsum -> part_out   (b linearity: b2 = u_hat.(v0+v1))
template <int R>
__global__ __launch_bounds__(256) void caps_pass(
    const float* __restrict__ u,        // [B, C, I]
    const float* __restrict__ W,        // [C, M, O, I]
    const float* __restrict__ part_in,  // [SPLIT][B][128] (R>=1)
    const float* __restrict__ v0_in,    // [B][128] (R==2)
    float* __restrict__ part_out,       // [SPLIT][B][128]
    float* __restrict__ v0_out)         // [B][128] (R==1)
{
    const int b   = blockIdx.x % B_SZ;
    const int sp  = blockIdx.x / B_SZ;
    const int tid = threadIdx.x;

    __shared__ float sh_v[M_SZ][O_SZ + 1];
    __shared__ float sh_part[256][O_SZ + 1];

    if (R >= 1) {
        if (tid < 128) {
            float s = 0.f;
#pragma unroll
            for (int k = 0; k < SPLIT; ++k)
                s += part_in[(k * B_SZ + b) * 128 + tid];
            float n2 = s * s;
            n2 += __shfl_xor(n2, 1);
            n2 += __shfl_xor(n2, 2);
            n2 += __shfl_xor(n2, 4);
            n2 += __shfl_xor(n2, 8);   // 16-lane group = one m row
            float norm = sqrtf(n2);
            float v = (n2 / (1.f + n2)) * s / (norm + CAPS_EPS);
            int m = tid >> 4, o = tid & 15;
            if (R == 1) {
                if (sp == 0) v0_out[b * 128 + tid] = v;
                sh_v[m][o] = v;
            } else {
                sh_v[m][o] = v + v0_in[b * 128 + tid];
            }
        }
        __syncthreads();
    }

    const int c_local = tid >> 3;  // 0..31
    const int m       = tid & 7;

    float s_acc[O_SZ];
#pragma unroll
    for (int o = 0; o < O_SZ; ++o) s_acc[o] = 0.f;

    const int c_base = sp * CPB;
#pragma unroll
    for (int cc = 0; cc < CPB; cc += 32) {
        const int c = c_base + cc + c_local;

        const float4* up = reinterpret_cast<const float4*>(
            u + (size_t)(b * C_SZ + c) * I_SZ);
        float4 u0 = up[0], u1 = up[1];
        float u8[8] = {u0.x, u0.y, u0.z, u0.w, u1.x, u1.y, u1.z, u1.w};

        float uh[O_SZ];
        const float4* wp = reinterpret_cast<const float4*>(
            W + (size_t)((c * M_SZ + m) * O_SZ) * I_SZ);
#pragma unroll
        for (int o = 0; o < O_SZ; ++o) {
            float4 w0 = wp[o * 2], w1 = wp[o * 2 + 1];
            uh[o] = w0.x * u8[0] + w0.y * u8[1] + w0.z * u8[2] + w0.w * u8[3] +
                    w1.x * u8[4] + w1.y * u8[5] + w1.z * u8[6] + w1.w * u8[7];
        }

        float cw;
        if (R == 0) {
            cw = 0.125f;  // softmax of zeros over M=8
        } else {
            float uv = 0.f;
#pragma unroll
            for (int o = 0; o < O_SZ; ++o) uv = fmaf(uh[o], sh_v[m][o], uv);
            float mx = uv;
            mx = fmaxf(mx, __shfl_xor(mx, 1));
            mx = fmaxf(mx, __shfl_xor(mx, 2));
            mx = fmaxf(mx, __shfl_xor(mx, 4));
            float e = expf(uv - mx);
            float den = e;
            den += __shfl_xor(den, 1);
            den += __shfl_xor(den, 2);
            den += __shfl_xor(den, 4);
            cw = e / den;
        }

#pragma unroll
        for (int o = 0; o < O_SZ; ++o) s_acc[o] = fmaf(cw, uh[o], s_acc[o]);
    }

#pragma unroll
    for (int o = 0; o < O_SZ; ++o) sh_part[tid][o] = s_acc[o];
    __syncthreads();

    if (tid < 128) {
        const int m2 = tid >> 4, o2 = tid & 15;
        float s = 0.f;
#pragma unroll
        for (int g = 0; g < 32; ++g) s += sh_part[g * 8 + m2][o2];
        part_out[(sp * B_SZ + b) * 128 + tid] = s;
    }
}

// Final reduce over SPLIT + squash -> out. grid = B, block = 128.
__global__ __launch_bounds__(128) void caps_finalize(
    const float* __restrict__ part_in,  // [SPLIT][B][128]
    float* __restrict__ out)            // [B][128]
{
    const int b   = blockIdx.x;
    const int tid = threadIdx.x;
    float s = 0.f;
#pragma unroll
    for (int k = 0; k < SPLIT; ++k)
        s += part_in[(k * B_SZ + b) * 128 + tid];
    float n2 = s * s;
    n2 += __shfl_xor(n2, 1);
    n2 += __shfl_xor(n2, 2);
    n2 += __shfl_xor(n2, 4);
    n2 += __shfl_xor(n2, 8);
    float norm = sqrtf(n2);
    out[b * 128 + tid] = (n2 / (1.f + n2)) * s / (norm + CAPS_EPS);
}

extern "C" void kernel_launch(void* const* d_in, const int* in_sizes, int n_in,
                              void* d_out, int out_size, void* d_ws, size_t ws_size,
                              hipStream_t stream) {
    const float* u = (const float*)d_in[0];  // [256,1152,8]
    const float* W = (const float*)d_in[1];  // [1152,8,16,8]
    float* out = (float*)d_out;              // [256,8,16]

    const int PART = SPLIT * B_SZ * 128;     // 294912 floats = 1.18 MB
    float* partA = (float*)d_ws;             // pass0 out / pass2 out (reused)
    float* partB = partA + PART;             // pass1 out
    float* v0    = partB + PART;             // [B][128]
    // total ws use: ~2.5 MB

    dim3 grid(SPLIT * B_SZ), block(256);
    caps_pass<0><<<grid, block, 0, stream>>>(u, W, nullptr, nullptr, partA, nullptr);
    caps_pass<1><<<grid, block, 0, stream>>>(u, W, partA, nullptr, partB, v0);
    caps_pass<2><<<grid, block, 0, stream>>>(u, W, partB, v0, partA, nullptr);
    caps_finalize<<<dim3(B_SZ), dim3(128), 0, stream>>>(partA, out);
}

// Round 3
// 79.814 us; speedup vs baseline: 5.9648x; 5.9648x over previous
//
#include <hip/hip_runtime.h>

#define B_SZ 256
#define C_SZ 1152
#define MO   128            // M*O = 8*16
#define CSPL 32
#define CRNG (C_SZ / CSPL)  // 36 capsules per block
#define CAPS_EPS 1e-8f

struct alignas(8) H4 { _Float16 h[4]; };

// ---------------------------------------------------------------------------
// K1: u_hat[c,b,mo] (fp16) + R=0 partial sums (uniform c weights = 1/8).
// grid = CSPL*32 (csp = blk>>5, b-tile = blk&31), block = 256 = 8 groups x 32.
// Group g owns b = bt*8+g; lane l owns mo = l*4 .. l*4+3.
// W[c] is staged transposed (i-major) in LDS so both the global read
// (256 consecutive float4) and the LDS read (32 contiguous float4 per i,
// broadcast across the wave's 2 groups) are conflict-free.
__global__ __launch_bounds__(256) void caps_uhat(
    const float* __restrict__ u,     // [B,C,8]
    const float* __restrict__ W,     // [C,128,8]
    H4* __restrict__ uhat,           // [C,B,32]  (H4 units: 4 fp16)
    float* __restrict__ part0)       // [CSPL,B,128]
{
    const int bt  = blockIdx.x & 31;
    const int csp = blockIdx.x >> 5;
    const int tid = threadIdx.x;
    const int g   = tid >> 5;
    const int l   = tid & 31;
    const int b   = bt * 8 + g;
    const int mo4 = l * 4;

    __shared__ __align__(16) float wT[8][132];   // i-major, padded

    float acc[4] = {0.f, 0.f, 0.f, 0.f};
    const int cbeg = csp * CRNG, cend = cbeg + CRNG;

    for (int c = cbeg; c < cend; ++c) {
        __syncthreads();   // protect previous iter's wT reads
        {   // stage W[c] transposed: thread t loads float4 (mo=t>>1, i0=(t&1)*4)
            const float4 wv = *reinterpret_cast<const float4*>(
                W + (size_t)c * 1024 + tid * 4);
            const int mo = tid >> 1, i0 = (tid & 1) * 4;
            wT[i0 + 0][mo] = wv.x; wT[i0 + 1][mo] = wv.y;
            wT[i0 + 2][mo] = wv.z; wT[i0 + 3][mo] = wv.w;
        }
        __syncthreads();

        const float4* up = reinterpret_cast<const float4*>(
            u + ((size_t)b * C_SZ + c) * 8);
        float4 u0 = up[0], u1 = up[1];
        float u8[8] = {u0.x, u0.y, u0.z, u0.w, u1.x, u1.y, u1.z, u1.w};

        float uh[4] = {0.f, 0.f, 0.f, 0.f};
#pragma unroll
        for (int i = 0; i < 8; ++i) {
            float4 w4 = *reinterpret_cast<const float4*>(&wT[i][mo4]);
            uh[0] = fmaf(w4.x, u8[i], uh[0]);
            uh[1] = fmaf(w4.y, u8[i], uh[1]);
            uh[2] = fmaf(w4.z, u8[i], uh[2]);
            uh[3] = fmaf(w4.w, u8[i], uh[3]);
        }
        H4 hv;
        hv.h[0] = (_Float16)uh[0]; hv.h[1] = (_Float16)uh[1];
        hv.h[2] = (_Float16)uh[2]; hv.h[3] = (_Float16)uh[3];
        uhat[((size_t)c * B_SZ + b) * 32 + l] = hv;   // group: 256B contiguous
#pragma unroll
        for (int j = 0; j < 4; ++j) acc[j] += uh[j];
    }
    *reinterpret_cast<float4*>(part0 + ((size_t)csp * B_SZ + b) * MO + mo4) =
        make_float4(acc[0] * 0.125f, acc[1] * 0.125f,
                    acc[2] * 0.125f, acc[3] * 0.125f);
}

// ---------------------------------------------------------------------------
// vcalc: vout = squash(sum_k part_in[k]) (+ addv if non-null).
// Used for v0, vsum = v1+v0, and the final output. grid = B, block = 128.
__global__ __launch_bounds__(128) void caps_vcalc(
    const float* __restrict__ part_in,  // [CSPL,B,128]
    const float* __restrict__ addv,     // [B,128] or null
    float* __restrict__ vout)           // [B,128]
{
    const int b = blockIdx.x, t = threadIdx.x;
    float s = 0.f;
#pragma unroll
    for (int k = 0; k < CSPL; ++k)
        s += part_in[((size_t)k * B_SZ + b) * MO + t];
    float n2 = s * s;                   // 16-lane group = one m row
    n2 += __shfl_xor(n2, 1);
    n2 += __shfl_xor(n2, 2);
    n2 += __shfl_xor(n2, 4);
    n2 += __shfl_xor(n2, 8);
    float norm = sqrtf(n2);
    float v = (n2 / (1.f + n2)) * s / (norm + CAPS_EPS);
    if (addv) v += addv[(size_t)b * MO + t];
    vout[(size_t)b * MO + t] = v;
}

// ---------------------------------------------------------------------------
// route: one routing pass over materialized u_hat.
// logits uv[m] via in-register dot + shuffles; softmax over m via xor 4/8/16;
// partial s accumulated per lane, written per (csp,b). Prefetch depth 2.
__global__ __launch_bounds__(256) void caps_route(
    const H4* __restrict__ uhat,        // [C,B,32]
    const float* __restrict__ vbuf,     // [B,128]
    float* __restrict__ part_out)       // [CSPL,B,128]
{
    const int bt  = blockIdx.x & 31;
    const int csp = blockIdx.x >> 5;
    const int tid = threadIdx.x;
    const int g   = tid >> 5;
    const int l   = tid & 31;
    const int b   = bt * 8 + g;
    const int mo4 = l * 4;

    const float4 v4 = *reinterpret_cast<const float4*>(
        vbuf + (size_t)b * MO + mo4);
    float acc[4] = {0.f, 0.f, 0.f, 0.f};

    const int cbeg = csp * CRNG, cend = cbeg + CRNG;
    const H4* base = uhat + (size_t)b * 32 + l;  // stride B_SZ*32 per c

    H4 r0 = base[(size_t)cbeg * B_SZ * 32];
    H4 r1 = base[(size_t)(cbeg + 1) * B_SZ * 32];

    for (int c = cbeg; c < cend; c += 2) {
        H4 n0 = r0, n1 = r1;
        if (c + 2 < cend) {
            n0 = base[(size_t)(c + 2) * B_SZ * 32];
            n1 = base[(size_t)(c + 3) * B_SZ * 32];
        }
#pragma unroll
        for (int q = 0; q < 2; ++q) {
            H4 r = q ? r1 : r0;
            float uh0 = (float)r.h[0], uh1 = (float)r.h[1];
            float uh2 = (float)r.h[2], uh3 = (float)r.h[3];
            float uv = uh0 * v4.x + uh1 * v4.y + uh2 * v4.z + uh3 * v4.w;
            uv += __shfl_xor(uv, 1);          // reduce over o-quarters
            uv += __shfl_xor(uv, 2);          // -> uv[m] on 4 lanes
            float mx = fmaxf(uv, __shfl_xor(uv, 4));
            mx = fmaxf(mx, __shfl_xor(mx, 8));
            mx = fmaxf(mx, __shfl_xor(mx, 16));
            float e = expf(uv - mx);
            float den = e;
            den += __shfl_xor(den, 4);
            den += __shfl_xor(den, 8);
            den += __shfl_xor(den, 16);
            float cw = e / den;
            acc[0] = fmaf(cw, uh0, acc[0]);
            acc[1] = fmaf(cw, uh1, acc[1]);
            acc[2] = fmaf(cw, uh2, acc[2]);
            acc[3] = fmaf(cw, uh3, acc[3]);
        }
        r0 = n0; r1 = n1;
    }
    *reinterpret_cast<float4*>(part_out + ((size_t)csp * B_SZ + b) * MO + mo4) =
        make_float4(acc[0], acc[1], acc[2], acc[3]);
}

// ---------------------------------------------------------------------------
// Fallback (small-ws): round-1 fused kernel, needs only 384 KB of ws.
template <int R>
__global__ __launch_bounds__(256) void caps_small(
    const float* __restrict__ u, const float* __restrict__ W,
    const float* __restrict__ s_in, const float* __restrict__ v0_in,
    float* __restrict__ s_out, float* __restrict__ v0_out,
    float* __restrict__ out)
{
    const int b = blockIdx.x, tid = threadIdx.x;
    __shared__ float sh_v[8][17];
    __shared__ float sh_part[256][17];

    if (R >= 1) {
        if (tid < 128) {
            float val = s_in[b * 128 + tid];
            float n2 = val * val;
            n2 += __shfl_xor(n2, 1); n2 += __shfl_xor(n2, 2);
            n2 += __shfl_xor(n2, 4); n2 += __shfl_xor(n2, 8);
            float norm = sqrtf(n2);
            float v = (n2 / (1.f + n2)) * val / (norm + CAPS_EPS);
            int m = tid >> 4, o = tid & 15;
            if (R == 1) { v0_out[b * 128 + tid] = v; sh_v[m][o] = v; }
            else        { sh_v[m][o] = v + v0_in[b * 128 + tid]; }
        }
        __syncthreads();
    }
    const int c_local = tid >> 3, m = tid & 7;
    float s_acc[16];
#pragma unroll
    for (int o = 0; o < 16; ++o) s_acc[o] = 0.f;
    for (int cc = 0; cc < C_SZ; cc += 32) {
        const int c = cc + c_local;
        const float4* up = reinterpret_cast<const float4*>(
            u + (size_t)(b * C_SZ + c) * 8);
        float4 u0 = up[0], u1 = up[1];
        float u8[8] = {u0.x, u0.y, u0.z, u0.w, u1.x, u1.y, u1.z, u1.w};
        float uh[16];
        const float4* wp = reinterpret_cast<const float4*>(
            W + (size_t)((c * 8 + m) * 16) * 8);
#pragma unroll
        for (int o = 0; o < 16; ++o) {
            float4 w0 = wp[o * 2], w1 = wp[o * 2 + 1];
            uh[o] = w0.x * u8[0] + w0.y * u8[1] + w0.z * u8[2] + w0.w * u8[3] +
                    w1.x * u8[4] + w1.y * u8[5] + w1.z * u8[6] + w1.w * u8[7];
        }
        float cw;
        if (R == 0) cw = 0.125f;
        else {
            float uv = 0.f;
#pragma unroll
            for (int o = 0; o < 16; ++o) uv = fmaf(uh[o], sh_v[m][o], uv);
            float mx = uv;
            mx = fmaxf(mx, __shfl_xor(mx, 1));
            mx = fmaxf(mx, __shfl_xor(mx, 2));
            mx = fmaxf(mx, __shfl_xor(mx, 4));
            float e = expf(uv - mx);
            float den = e;
            den += __shfl_xor(den, 1); den += __shfl_xor(den, 2);
            den += __shfl_xor(den, 4);
            cw = e / den;
        }
#pragma unroll
        for (int o = 0; o < 16; ++o) s_acc[o] = fmaf(cw, uh[o], s_acc[o]);
    }
#pragma unroll
    for (int o = 0; o < 16; ++o) sh_part[tid][o] = s_acc[o];
    __syncthreads();
    if (tid < 128) {
        const int m2 = tid >> 4, o2 = tid & 15;
        float s = 0.f;
#pragma unroll
        for (int gg = 0; gg < 32; ++gg) s += sh_part[gg * 8 + m2][o2];
        if (R < 2) s_out[b * 128 + tid] = s;
        else {
            float n2 = s * s;
            n2 += __shfl_xor(n2, 1); n2 += __shfl_xor(n2, 2);
            n2 += __shfl_xor(n2, 4); n2 += __shfl_xor(n2, 8);
            float norm = sqrtf(n2);
            out[b * 128 + tid] = (n2 / (1.f + n2)) * s / (norm + CAPS_EPS);
        }
    }
}

extern "C" void kernel_launch(void* const* d_in, const int* in_sizes, int n_in,
                              void* d_out, int out_size, void* d_ws, size_t ws_size,
                              hipStream_t stream) {
    const float* u = (const float*)d_in[0];  // [256,1152,8]
    const float* W = (const float*)d_in[1];  // [1152,8,16,8]
    float* out = (float*)d_out;              // [256,8,16]

    const size_t UHAT_ELEMS = (size_t)C_SZ * B_SZ * 32;          // H4 units
    const size_t UHAT_BYTES = UHAT_ELEMS * 8;                    // 75.5 MB
    const size_t PART_FLOATS = (size_t)CSPL * B_SZ * MO;         // 4.19 MB
    const size_t NEED = UHAT_BYTES + 2 * PART_FLOATS * 4 + 2 * B_SZ * MO * 4;

    if (ws_size >= NEED) {
        H4* uhat     = (H4*)d_ws;
        float* partA = (float*)((char*)d_ws + UHAT_BYTES);
        float* partB = partA + PART_FLOATS;
        float* v0    = partB + PART_FLOATS;
        float* vsum  = v0 + B_SZ * MO;

        dim3 gridC(CSPL * 32), blk(256);
        caps_uhat <<<gridC, blk, 0, stream>>>(u, W, uhat, partA);
        caps_vcalc<<<dim3(B_SZ), dim3(128), 0, stream>>>(partA, nullptr, v0);
        caps_route<<<gridC, blk, 0, stream>>>(uhat, v0, partB);
        caps_vcalc<<<dim3(B_SZ), dim3(128), 0, stream>>>(partB, v0, vsum);
        caps_route<<<gridC, blk, 0, stream>>>(uhat, vsum, partA);
        caps_vcalc<<<dim3(B_SZ), dim3(128), 0, stream>>>(partA, nullptr, out);
    } else {
        // small-ws fallback (round-1 path)
        float* sA = (float*)d_ws;
        float* sB = sA + 32768;
        float* v0 = sB + 32768;
        dim3 grid(B_SZ), blk(256);
        caps_small<0><<<grid, blk, 0, stream>>>(u, W, nullptr, nullptr, sA, nullptr, nullptr);
        caps_small<1><<<grid, blk, 0, stream>>>(u, W, sA, nullptr, sB, v0, nullptr);
        caps_small<2><<<grid, blk, 0, stream>>>(u, W, sB, v0, nullptr, nullptr, out);
    }
}